// Round 5
// baseline (638.425 us; speedup 1.0000x reference)
//
#include <hip/hip_runtime.h>
#include <cstdint>

// LSTM cell: B=4096, N_IN=2048, N_OUT=2048.
// gates = [x|h_old](4096x4096) @ Wp^T + b ; Wp rows gate-interleaved: Wp[4j+q]=W_q[j].
// R8 = R4's schedule byte-identical (best measured: 374us, Mfma 31.7) + memory-system fixes:
//   (1) 8m x 8n per-XCD block regions (concurrent-32/XCD = 8m x 4n): 8 readers/A-panel,
//       4 readers/B-panel through XCD-L2, K-slice working set ~600KB << 4MB L2.
//   (2) nt-load c_old, nt-store c_out/h_out, nt-load pack inputs: stop Infinity-Cache
//       thrash of the T/Wp working set (FETCH was 558MB vs 128MB ideal).
//   (3) pack uses v_cvt_pk_bf16_f32 (same RNE bits, fewer VALU).
// ws layout: t bf16 (32MB) @0, Wp bf16 (64MB) @32MB. Requires ws_size >= 96MB.

#define B_DIM 4096
#define NIN   2048
#define NOUT  2048
#define K_DIM 4096   // NIN + NOUT
#define NG    8192   // 4 * NOUT

#define BM 256
#define BN 256
#define BK 64
#define NT      (K_DIM / BK)   // 64 K-tiles
#define NSTREAM (NT * 4)       // 256 half-tiles in the staging stream

typedef __attribute__((ext_vector_type(8))) short bf16x8;  // 8 bf16 = 4 VGPRs
typedef __attribute__((ext_vector_type(4))) float f32x4;
typedef __attribute__((ext_vector_type(4))) float fx4;

__device__ inline uint32_t cvtpk(float a, float b) {   // lo16=bf16(a), hi16=bf16(b), RNE
    uint32_t r;
    asm("v_cvt_pk_bf16_f32 %0, %1, %2" : "=v"(r) : "v"(a), "v"(b));
    return r;
}

__device__ inline float sel4(float a, float b, float c, float d, int s) {
    float x = (s & 1) ? b : a;
    float y = (s & 1) ? d : c;
    return (s & 2) ? y : x;
}

// ---- combined pack kernel ----
#define TBLK ((B_DIM * K_DIM / 8) / 256)   // 8192
#define WBLK ((NG * K_DIM / 8) / 256)      // 16384
__global__ void pack_kernel(const float* __restrict__ x,
                            const float* __restrict__ h_old,
                            const float* __restrict__ Wf, const float* __restrict__ Wi,
                            const float* __restrict__ Wo, const float* __restrict__ Wg,
                            unsigned short* __restrict__ t,
                            unsigned short* __restrict__ Wp) {
    const float* src;
    unsigned short* dst;
    int idx;
    if (blockIdx.x < TBLK) {
        idx = blockIdx.x * 256 + threadIdx.x;
        int b = idx >> 9;                                 // K/8 = 512 chunks/row
        int k = (idx & 511) << 3;
        src = (k < NIN) ? (x + (size_t)b * NIN + k)
                        : (h_old + (size_t)b * NOUT + (k - NIN));
        dst = t;
    } else {
        idx = (blockIdx.x - TBLK) * 256 + threadIdx.x;
        int row = idx >> 9;
        int k = (idx & 511) << 3;
        int jf = row >> 2, q = row & 3;
        src = ((q == 0) ? Wf : (q == 1) ? Wi : (q == 2) ? Wo : Wg)
              + (size_t)jf * K_DIM + k;
        dst = Wp;
    }
    // nt-loads: inputs are read-once; keep them out of L2/L3 so T/Wp stay resident.
    fx4 lo = __builtin_nontemporal_load((const fx4*)src);
    fx4 hi = __builtin_nontemporal_load(((const fx4*)src) + 1);
    uint4 o;
    o.x = cvtpk(lo.x, lo.y);
    o.y = cvtpk(lo.z, lo.w);
    o.z = cvtpk(hi.x, hi.y);
    o.w = cvtpk(hi.z, hi.w);
    ((uint4*)dst)[idx] = o;   // normal store: t/Wp SHOULD be cached for the GEMM
}

#define GL2LDS(g, l) \
    __builtin_amdgcn_global_load_lds((const __attribute__((address_space(1))) void*)(g), \
                                     (__attribute__((address_space(3))) void*)(l), 16, 0, 0)

#define ASM_VMCNT4() asm volatile("s_waitcnt vmcnt(4)" ::: "memory")
#define ASM_VMCNT0() asm volatile("s_waitcnt vmcnt(0)" ::: "memory")
#define ASM_LGKM0()  asm volatile("s_waitcnt lgkmcnt(0)" ::: "memory")
#define BAR()        __builtin_amdgcn_s_barrier()

// Staging stream: half-tile idx -> tile=idx>>2, operand=idx&1 (0=A/T,1=B/Wp),
// half h=(idx>>1)&1 (rows h*128..h*128+127). Each thread: 2 x 16B loads.
// LDS dest linear (tid*16B); global source chunk pre-swizzled: c = (tid&7)^((tid>>3)&7).
#define STAGE(idx_) do {                                                          \
    const int _i = (idx_);                                                        \
    if (_i < NSTREAM) {                                                           \
        const int _tile = _i >> 2;                                                \
        const int _h    = (_i >> 1) & 1;                                          \
        const int _buf  = _tile & 1;                                              \
        const unsigned short* _g = ((_i & 1) ? Wg : Tg)                           \
                                   + (size_t)(_h * 128) * K_DIM + _tile * BK;     \
        unsigned short* _l = ((_i & 1) ? Bs : As)                                 \
                             + _buf * (BM * BK) + _h * 8192 + ldst;               \
        GL2LDS(_g, _l);                                                           \
        GL2LDS(_g + (size_t)64 * K_DIM, _l + 4096);                               \
    }                                                                             \
} while (0)

// ---- fused GEMM + LSTM epilogue: 256x256 tile, 8 waves, 8-phase schedule ----
__global__ __launch_bounds__(512, 1)
void lstm_gemm_kernel(const unsigned short* __restrict__ T,   // (B, K) bf16
                      const unsigned short* __restrict__ Wp,  // (NG, K) bf16
                      const float* __restrict__ bf_, const float* __restrict__ bi_,
                      const float* __restrict__ bo_, const float* __restrict__ bg_,
                      const float* __restrict__ c_old,
                      float* __restrict__ c_out, float* __restrict__ h_out) {
    __shared__ __align__(16) unsigned short As[2 * BM * BK];  // 64 KB
    __shared__ __align__(16) unsigned short Bs[2 * BN * BK];  // 64 KB

    const int tid  = threadIdx.x;
    const int lane = tid & 63;
    const int w    = tid >> 6;     // 0..7
    const int wr   = w >> 2;       // 0..1 (M)
    const int wc   = w & 3;        // 0..3 (N)

    // 8m x 8n region per XCD (bid&7 = XCD under round-robin dispatch).
    // Concurrent 32 blocks/XCD (intra 0..31) form an 8m x 4n rectangle:
    // 8 same-L2 readers per A-panel, 4 per B-panel; K-slice set ~600KB fits L2.
    const int bid   = blockIdx.x;
    const int xcd   = bid & 7;
    const int intra = bid >> 3;                        // 0..63
    const int mi    = (xcd >> 2) * 8 + (intra & 7);    // 0..15
    const int ni    = (xcd & 3) * 8 + (intra >> 3);    // 0..31
    const int m0    = mi * BM;
    const int n0    = ni * BN;

    // staging per-thread constants
    const int rloc = tid >> 3;                                   // row 0..63
    const int coff = ((tid & 7) ^ ((tid >> 3) & 7)) << 3;        // swizzled src chunk
    const unsigned short* Tg = T  + (size_t)(m0 + rloc) * K_DIM + coff;
    const unsigned short* Wg = Wp + (size_t)(n0 + rloc) * K_DIM + coff;
    const int ldst = tid * 8;   // element offset within (buf, half) block

    // frag-read constants: chunk = (s*4 + ksel) ^ (row&7), row&7 == lane&7 here
    const int rsel = lane & 15, ksel = lane >> 4;
    const int cs0 = (ksel)     ^ (lane & 7);
    const int cs1 = (4 + ksel) ^ (lane & 7);
    const int aidx = (wr * 128 + rsel) * 8;   // + i*128 (+ 64*8 for half1) + cs
    const int bidx = (wc * 64  + rsel) * 8;   // + j*128 (+ 32*8 for half1) + cs

    const bf16x8* Av = (const bf16x8*)As;
    const bf16x8* Bv = (const bf16x8*)Bs;

    f32x4 acc[8][4];
#pragma unroll
    for (int i = 0; i < 8; ++i)
#pragma unroll
        for (int j = 0; j < 4; ++j)
            acc[i][j] = (f32x4){0.f, 0.f, 0.f, 0.f};

    // ---- prologue: stream 0..5 (tile0 complete + tile1 A0,B0), land tile0 ----
    STAGE(0); STAGE(1); STAGE(2); STAGE(3); STAGE(4); STAGE(5);
    ASM_VMCNT4();
    BAR();

    bf16x8 a0[4][2], a1[4][2], bfr[2][2];

#pragma unroll 2
    for (int t = 0; t < NT; ++t) {
        const int bo = (t & 1) * 2048;   // bf16x8 buffer offset

        // ---- P1: read A-half0 + B-half0, stage (t+1).A1 ----
#pragma unroll
        for (int i = 0; i < 4; ++i) {
            a0[i][0] = Av[bo + aidx + i * 128 + cs0];
            a0[i][1] = Av[bo + aidx + i * 128 + cs1];
        }
#pragma unroll
        for (int j = 0; j < 2; ++j) {
            bfr[j][0] = Bv[bo + bidx + j * 128 + cs0];
            bfr[j][1] = Bv[bo + bidx + j * 128 + cs1];
        }
        STAGE(4 * t + 6);
        BAR();
        ASM_LGKM0();
        __builtin_amdgcn_s_setprio(1);
#pragma unroll
        for (int i = 0; i < 4; ++i)
#pragma unroll
            for (int j = 0; j < 2; ++j)
#pragma unroll
                for (int s = 0; s < 2; ++s)
                    acc[i][j] = __builtin_amdgcn_mfma_f32_16x16x32_bf16(
                        a0[i][s], bfr[j][s], acc[i][j], 0, 0, 0);
        __builtin_amdgcn_s_setprio(0);
        BAR();

        // ---- P2: read A-half1, stage (t+1).B1 ----
#pragma unroll
        for (int i = 0; i < 4; ++i) {
            a1[i][0] = Av[bo + aidx + 512 + i * 128 + cs0];
            a1[i][1] = Av[bo + aidx + 512 + i * 128 + cs1];
        }
        STAGE(4 * t + 7);
        BAR();
        ASM_LGKM0();
        __builtin_amdgcn_s_setprio(1);
#pragma unroll
        for (int i = 0; i < 4; ++i)
#pragma unroll
            for (int j = 0; j < 2; ++j)
#pragma unroll
                for (int s = 0; s < 2; ++s)
                    acc[4 + i][j] = __builtin_amdgcn_mfma_f32_16x16x32_bf16(
                        a1[i][s], bfr[j][s], acc[4 + i][j], 0, 0, 0);
        __builtin_amdgcn_s_setprio(0);
        BAR();

        // ---- P3: read B-half1, stage (t+2).A0 ----
#pragma unroll
        for (int j = 0; j < 2; ++j) {
            bfr[j][0] = Bv[bo + bidx + 256 + j * 128 + cs0];
            bfr[j][1] = Bv[bo + bidx + 256 + j * 128 + cs1];
        }
        STAGE(4 * t + 8);
        BAR();
        ASM_LGKM0();
        __builtin_amdgcn_s_setprio(1);
#pragma unroll
        for (int i = 0; i < 4; ++i)
#pragma unroll
            for (int j = 0; j < 2; ++j)
#pragma unroll
                for (int s = 0; s < 2; ++s)
                    acc[4 + i][2 + j] = __builtin_amdgcn_mfma_f32_16x16x32_bf16(
                        a1[i][s], bfr[j][s], acc[4 + i][2 + j], 0, 0, 0);
        __builtin_amdgcn_s_setprio(0);
        BAR();

        // ---- P4: no reads (A-half0 kept in regs), stage (t+2).B0 ----
        STAGE(4 * t + 9);
        BAR();
        __builtin_amdgcn_s_setprio(1);
#pragma unroll
        for (int s = 0; s < 2; ++s)
#pragma unroll
            for (int i = 0; i < 4; ++i)
#pragma unroll
                for (int j = 0; j < 2; ++j)
                    acc[i][2 + j] = __builtin_amdgcn_mfma_f32_16x16x32_bf16(
                        a0[i][s], bfr[j][s], acc[i][2 + j], 0, 0, 0);
        __builtin_amdgcn_s_setprio(0);
        if (t < NT - 2) { ASM_VMCNT4(); } else { ASM_VMCNT0(); }
        BAR();
    }

    // ---- epilogue (identical logic; c_old/c_out/h_out made non-temporal) ----
    // C/D map (16x16x32): col = lane&15, row = (lane>>4)*4 + r.
    // col n = n0+wc*64+16j+(lane&15): gate q = n&3 = lane&3, feature = n>>2.
    const int q = lane & 3;
    const float* bsrc = (q == 0) ? bf_ : (q == 1) ? bi_ : (q == 2) ? bo_ : bg_;
    const int colbase = n0 + wc * 64 + (lane & 15);
    float bias[4];
#pragma unroll
    for (int j = 0; j < 4; ++j)
        bias[j] = bsrc[(colbase + 16 * j) >> 2];

    const int rowbase = m0 + wr * 128 + 4 * (lane >> 4);
#pragma unroll
    for (int i = 0; i < 8; ++i) {
#pragma unroll
        for (int j = 0; j < 4; ++j) {
            const int featbase = (n0 + wc * 64 + 16 * j) >> 2;
#pragma unroll
            for (int r = 0; r < 4; ++r) {
                float z = acc[i][j][r] + bias[j];
                float v;
                if (q == 3) {                         // tanh for gate g
                    v = 1.f - 2.f / (__expf(2.f * z) + 1.f);
                } else {                              // sigmoid for f,i,o
                    v = 1.f / (1.f + __expf(-z));
                }
                float v1 = __shfl_xor(v, 1);
                float v2 = __shfl_xor(v, 2);
                float v3 = __shfl_xor(v, 3);
                float fg = sel4(v, v1, v2, v3, q);
                float ig = sel4(v, v1, v2, v3, q ^ 1);
                float og = sel4(v, v1, v2, v3, q ^ 2);
                float gg = sel4(v, v1, v2, v3, q ^ 3);
                if ((lane & 3) == r) {
                    const int row  = rowbase + 16 * i + r;
                    const int feat = featbase + ((lane & 15) >> 2);
                    const size_t off = (size_t)row * NOUT + feat;
                    float co = __builtin_nontemporal_load(c_old + off);
                    float c  = fg * co + ig * gg;
                    float h  = og * (1.f - 2.f / (__expf(2.f * c) + 1.f));
                    __builtin_nontemporal_store(c, c_out + off);
                    __builtin_nontemporal_store(h, h_out + off);
                }
            }
        }
    }
}

extern "C" void kernel_launch(void* const* d_in, const int* in_sizes, int n_in,
                              void* d_out, int out_size, void* d_ws, size_t ws_size,
                              hipStream_t stream) {
    const float* c_old = (const float*)d_in[0];
    const float* h_old = (const float*)d_in[1];
    const float* x     = (const float*)d_in[2];
    const float* Wf    = (const float*)d_in[3];
    const float* bf_   = (const float*)d_in[4];
    const float* Wi    = (const float*)d_in[5];
    const float* bi_   = (const float*)d_in[6];
    const float* Wo    = (const float*)d_in[7];
    const float* bo_   = (const float*)d_in[8];
    const float* Wg    = (const float*)d_in[9];
    const float* bg_   = (const float*)d_in[10];

    unsigned short* t  = (unsigned short*)d_ws;                           // 32 MB
    unsigned short* Wp = (unsigned short*)d_ws + (size_t)B_DIM * K_DIM;   // 64 MB

    float* c_out = (float*)d_out;
    float* h_out = (float*)d_out + (size_t)B_DIM * NOUT;

    pack_kernel<<<TBLK + WBLK, 256, 0, stream>>>(x, h_old, Wf, Wi, Wo, Wg, t, Wp);

    lstm_gemm_kernel<<<dim3((B_DIM / BM) * (NG / BN)), dim3(512), 0, stream>>>(
        t, Wp, bf_, bi_, bo_, bg_, c_old, c_out, h_out);
}

// Round 6
// 563.359 us; speedup vs baseline: 1.1332x; 1.1332x over previous
//
#include <hip/hip_runtime.h>
#include <cstdint>

// LSTM cell: B=4096, N_IN=2048, N_OUT=2048.
// gates = [x|h_old](4096x4096) @ Wp^T + b ; Wp rows gate-interleaved: Wp[4j+q]=W_q[j].
// R9:
//   pack: grid-stride 2048 blocks (12 iter/thread), nt-loads, v_cvt_pk_bf16_f32,
//         plain stores (t/Wp stay L3-resident for the GEMM). Pack was ~1.4 TB/s
//         on 288 MB (should be ~50us) -- launch/ILP-bound, not BW-bound.
//   gemm: R4 schedule byte-identical (best: 374us/31.7%) + R8's 8m x 8n per-XCD
//         region mapping (FETCH 558->256 MB, verified) + epilogue reverted to
//         PLAIN loads/stores (R8's nt-stores caused 2.5x write amplification,
//         WRITE 65->160 MB = the whole +99us regression).
// ws layout: t bf16 (32MB) @0, Wp bf16 (64MB) @32MB. Requires ws_size >= 96MB.

#define B_DIM 4096
#define NIN   2048
#define NOUT  2048
#define K_DIM 4096   // NIN + NOUT
#define NG    8192   // 4 * NOUT

#define BM 256
#define BN 256
#define BK 64
#define NT      (K_DIM / BK)   // 64 K-tiles
#define NSTREAM (NT * 4)       // 256 half-tiles in the staging stream

typedef __attribute__((ext_vector_type(8))) short bf16x8;  // 8 bf16 = 4 VGPRs
typedef __attribute__((ext_vector_type(4))) float f32x4;
typedef __attribute__((ext_vector_type(4))) float fx4;

__device__ inline uint32_t cvtpk(float a, float b) {   // lo16=bf16(a), hi16=bf16(b), RNE
    uint32_t r;
    asm("v_cvt_pk_bf16_f32 %0, %1, %2" : "=v"(r) : "v"(a), "v"(b));
    return r;
}

__device__ inline float sel4(float a, float b, float c, float d, int s) {
    float x = (s & 1) ? b : a;
    float y = (s & 1) ? d : c;
    return (s & 2) ? y : x;
}

// ---- pack kernel: grid-stride, 2048 blocks x 256 thr x 12 iters ----
#define TOT_T (B_DIM * K_DIM / 8)            // 2,097,152 uint4 outputs for t
#define TOT_W (NG * K_DIM / 8)               // 4,194,304 uint4 outputs for Wp
#define PACK_BLOCKS 2048
#define PACK_ITERS  ((TOT_T + TOT_W) / (PACK_BLOCKS * 256))   // = 12 exact
__global__ void pack_kernel(const float* __restrict__ x,
                            const float* __restrict__ h_old,
                            const float* __restrict__ Wf, const float* __restrict__ Wi,
                            const float* __restrict__ Wo, const float* __restrict__ Wg,
                            unsigned short* __restrict__ t,
                            unsigned short* __restrict__ Wp) {
    int gid = blockIdx.x * 256 + threadIdx.x;
#pragma unroll 2
    for (int it = 0; it < PACK_ITERS; ++it, gid += PACK_BLOCKS * 256) {
        const float* src;
        unsigned short* dst;
        int idx;
        if (gid < TOT_T) {
            idx = gid;
            int b = idx >> 9;                                 // K/8 = 512 chunks/row
            int k = (idx & 511) << 3;
            src = (k < NIN) ? (x + (size_t)b * NIN + k)
                            : (h_old + (size_t)b * NOUT + (k - NIN));
            dst = t;
        } else {
            idx = gid - TOT_T;
            int row = idx >> 9;
            int k = (idx & 511) << 3;
            int jf = row >> 2, q = row & 3;
            src = ((q == 0) ? Wf : (q == 1) ? Wi : (q == 2) ? Wo : Wg)
                  + (size_t)jf * K_DIM + k;
            dst = Wp;
        }
        // nt-loads: inputs read-once; keep them out of L2/L3 so t/Wp stay resident.
        fx4 lo = __builtin_nontemporal_load((const fx4*)src);
        fx4 hi = __builtin_nontemporal_load(((const fx4*)src) + 1);
        uint4 o;
        o.x = cvtpk(lo.x, lo.y);
        o.y = cvtpk(lo.z, lo.w);
        o.z = cvtpk(hi.x, hi.y);
        o.w = cvtpk(hi.z, hi.w);
        ((uint4*)dst)[idx] = o;   // plain store: t/Wp cached for the GEMM
    }
}

#define GL2LDS(g, l) \
    __builtin_amdgcn_global_load_lds((const __attribute__((address_space(1))) void*)(g), \
                                     (__attribute__((address_space(3))) void*)(l), 16, 0, 0)

#define ASM_VMCNT4() asm volatile("s_waitcnt vmcnt(4)" ::: "memory")
#define ASM_VMCNT0() asm volatile("s_waitcnt vmcnt(0)" ::: "memory")
#define ASM_LGKM0()  asm volatile("s_waitcnt lgkmcnt(0)" ::: "memory")
#define BAR()        __builtin_amdgcn_s_barrier()

// Staging stream: half-tile idx -> tile=idx>>2, operand=idx&1 (0=A/T,1=B/Wp),
// half h=(idx>>1)&1 (rows h*128..h*128+127). Each thread: 2 x 16B loads.
// LDS dest linear (tid*16B); global source chunk pre-swizzled: c = (tid&7)^((tid>>3)&7).
#define STAGE(idx_) do {                                                          \
    const int _i = (idx_);                                                        \
    if (_i < NSTREAM) {                                                           \
        const int _tile = _i >> 2;                                                \
        const int _h    = (_i >> 1) & 1;                                          \
        const int _buf  = _tile & 1;                                              \
        const unsigned short* _g = ((_i & 1) ? Wg : Tg)                           \
                                   + (size_t)(_h * 128) * K_DIM + _tile * BK;     \
        unsigned short* _l = ((_i & 1) ? Bs : As)                                 \
                             + _buf * (BM * BK) + _h * 8192 + ldst;               \
        GL2LDS(_g, _l);                                                           \
        GL2LDS(_g + (size_t)64 * K_DIM, _l + 4096);                               \
    }                                                                             \
} while (0)

// ---- fused GEMM + LSTM epilogue: 256x256 tile, 8 waves, 8-phase schedule ----
__global__ __launch_bounds__(512, 1)
void lstm_gemm_kernel(const unsigned short* __restrict__ T,   // (B, K) bf16
                      const unsigned short* __restrict__ Wp,  // (NG, K) bf16
                      const float* __restrict__ bf_, const float* __restrict__ bi_,
                      const float* __restrict__ bo_, const float* __restrict__ bg_,
                      const float* __restrict__ c_old,
                      float* __restrict__ c_out, float* __restrict__ h_out) {
    __shared__ __align__(16) unsigned short As[2 * BM * BK];  // 64 KB
    __shared__ __align__(16) unsigned short Bs[2 * BN * BK];  // 64 KB

    const int tid  = threadIdx.x;
    const int lane = tid & 63;
    const int w    = tid >> 6;     // 0..7
    const int wr   = w >> 2;       // 0..1 (M)
    const int wc   = w & 3;        // 0..3 (N)

    // 8m x 8n region per XCD (bid&7 = XCD under round-robin dispatch).
    // Concurrent 32 blocks/XCD form an 8m x 4n rectangle: 8 same-L2 readers per
    // A-panel, 4 per B-panel; K-slice working set ~600KB fits the 4MB XCD L2.
    const int bid   = blockIdx.x;
    const int xcd   = bid & 7;
    const int intra = bid >> 3;                        // 0..63
    const int mi    = (xcd >> 2) * 8 + (intra & 7);    // 0..15
    const int ni    = (xcd & 3) * 8 + (intra >> 3);    // 0..31
    const int m0    = mi * BM;
    const int n0    = ni * BN;

    // staging per-thread constants
    const int rloc = tid >> 3;                                   // row 0..63
    const int coff = ((tid & 7) ^ ((tid >> 3) & 7)) << 3;        // swizzled src chunk
    const unsigned short* Tg = T  + (size_t)(m0 + rloc) * K_DIM + coff;
    const unsigned short* Wg = Wp + (size_t)(n0 + rloc) * K_DIM + coff;
    const int ldst = tid * 8;   // element offset within (buf, half) block

    // frag-read constants: chunk = (s*4 + ksel) ^ (row&7), row&7 == lane&7 here
    const int rsel = lane & 15, ksel = lane >> 4;
    const int cs0 = (ksel)     ^ (lane & 7);
    const int cs1 = (4 + ksel) ^ (lane & 7);
    const int aidx = (wr * 128 + rsel) * 8;   // + i*128 (+ 64*8 for half1) + cs
    const int bidx = (wc * 64  + rsel) * 8;   // + j*128 (+ 32*8 for half1) + cs

    const bf16x8* Av = (const bf16x8*)As;
    const bf16x8* Bv = (const bf16x8*)Bs;

    f32x4 acc[8][4];
#pragma unroll
    for (int i = 0; i < 8; ++i)
#pragma unroll
        for (int j = 0; j < 4; ++j)
            acc[i][j] = (f32x4){0.f, 0.f, 0.f, 0.f};

    // ---- prologue: stream 0..5 (tile0 complete + tile1 A0,B0), land tile0 ----
    STAGE(0); STAGE(1); STAGE(2); STAGE(3); STAGE(4); STAGE(5);
    ASM_VMCNT4();
    BAR();

    bf16x8 a0[4][2], a1[4][2], bfr[2][2];

#pragma unroll 2
    for (int t = 0; t < NT; ++t) {
        const int bo = (t & 1) * 2048;   // bf16x8 buffer offset

        // ---- P1: read A-half0 + B-half0, stage (t+1).A1 ----
#pragma unroll
        for (int i = 0; i < 4; ++i) {
            a0[i][0] = Av[bo + aidx + i * 128 + cs0];
            a0[i][1] = Av[bo + aidx + i * 128 + cs1];
        }
#pragma unroll
        for (int j = 0; j < 2; ++j) {
            bfr[j][0] = Bv[bo + bidx + j * 128 + cs0];
            bfr[j][1] = Bv[bo + bidx + j * 128 + cs1];
        }
        STAGE(4 * t + 6);
        BAR();
        ASM_LGKM0();
        __builtin_amdgcn_s_setprio(1);
#pragma unroll
        for (int i = 0; i < 4; ++i)
#pragma unroll
            for (int j = 0; j < 2; ++j)
#pragma unroll
                for (int s = 0; s < 2; ++s)
                    acc[i][j] = __builtin_amdgcn_mfma_f32_16x16x32_bf16(
                        a0[i][s], bfr[j][s], acc[i][j], 0, 0, 0);
        __builtin_amdgcn_s_setprio(0);
        BAR();

        // ---- P2: read A-half1, stage (t+1).B1 ----
#pragma unroll
        for (int i = 0; i < 4; ++i) {
            a1[i][0] = Av[bo + aidx + 512 + i * 128 + cs0];
            a1[i][1] = Av[bo + aidx + 512 + i * 128 + cs1];
        }
        STAGE(4 * t + 7);
        BAR();
        ASM_LGKM0();
        __builtin_amdgcn_s_setprio(1);
#pragma unroll
        for (int i = 0; i < 4; ++i)
#pragma unroll
            for (int j = 0; j < 2; ++j)
#pragma unroll
                for (int s = 0; s < 2; ++s)
                    acc[4 + i][j] = __builtin_amdgcn_mfma_f32_16x16x32_bf16(
                        a1[i][s], bfr[j][s], acc[4 + i][j], 0, 0, 0);
        __builtin_amdgcn_s_setprio(0);
        BAR();

        // ---- P3: read B-half1, stage (t+2).A0 ----
#pragma unroll
        for (int j = 0; j < 2; ++j) {
            bfr[j][0] = Bv[bo + bidx + 256 + j * 128 + cs0];
            bfr[j][1] = Bv[bo + bidx + 256 + j * 128 + cs1];
        }
        STAGE(4 * t + 8);
        BAR();
        ASM_LGKM0();
        __builtin_amdgcn_s_setprio(1);
#pragma unroll
        for (int i = 0; i < 4; ++i)
#pragma unroll
            for (int j = 0; j < 2; ++j)
#pragma unroll
                for (int s = 0; s < 2; ++s)
                    acc[4 + i][2 + j] = __builtin_amdgcn_mfma_f32_16x16x32_bf16(
                        a1[i][s], bfr[j][s], acc[4 + i][2 + j], 0, 0, 0);
        __builtin_amdgcn_s_setprio(0);
        BAR();

        // ---- P4: no reads (A-half0 kept in regs), stage (t+2).B0 ----
        STAGE(4 * t + 9);
        BAR();
        __builtin_amdgcn_s_setprio(1);
#pragma unroll
        for (int s = 0; s < 2; ++s)
#pragma unroll
            for (int i = 0; i < 4; ++i)
#pragma unroll
                for (int j = 0; j < 2; ++j)
                    acc[i][2 + j] = __builtin_amdgcn_mfma_f32_16x16x32_bf16(
                        a0[i][s], bfr[j][s], acc[i][2 + j], 0, 0, 0);
        __builtin_amdgcn_s_setprio(0);
        if (t < NT - 2) { ASM_VMCNT4(); } else { ASM_VMCNT0(); }
        BAR();
    }

    // ---- epilogue (plain loads/stores — R4 verbatim) ----
    // C/D map (16x16x32): col = lane&15, row = (lane>>4)*4 + r.
    // col n = n0+wc*64+16j+(lane&15): gate q = n&3 = lane&3, feature = n>>2.
    const int q = lane & 3;
    const float* bsrc = (q == 0) ? bf_ : (q == 1) ? bi_ : (q == 2) ? bo_ : bg_;
    const int colbase = n0 + wc * 64 + (lane & 15);
    float bias[4];
#pragma unroll
    for (int j = 0; j < 4; ++j)
        bias[j] = bsrc[(colbase + 16 * j) >> 2];

    const int rowbase = m0 + wr * 128 + 4 * (lane >> 4);
#pragma unroll
    for (int i = 0; i < 8; ++i) {
#pragma unroll
        for (int j = 0; j < 4; ++j) {
            const int featbase = (n0 + wc * 64 + 16 * j) >> 2;
#pragma unroll
            for (int r = 0; r < 4; ++r) {
                float z = acc[i][j][r] + bias[j];
                float v;
                if (q == 3) {                         // tanh for gate g
                    v = 1.f - 2.f / (__expf(2.f * z) + 1.f);
                } else {                              // sigmoid for f,i,o
                    v = 1.f / (1.f + __expf(-z));
                }
                float v1 = __shfl_xor(v, 1);
                float v2 = __shfl_xor(v, 2);
                float v3 = __shfl_xor(v, 3);
                float fg = sel4(v, v1, v2, v3, q);
                float ig = sel4(v, v1, v2, v3, q ^ 1);
                float og = sel4(v, v1, v2, v3, q ^ 2);
                float gg = sel4(v, v1, v2, v3, q ^ 3);
                if ((lane & 3) == r) {
                    const int row  = rowbase + 16 * i + r;
                    const int feat = featbase + ((lane & 15) >> 2);
                    const size_t off = (size_t)row * NOUT + feat;
                    float co = c_old[off];
                    float c  = fg * co + ig * gg;
                    float h  = og * (1.f - 2.f / (__expf(2.f * c) + 1.f));
                    c_out[off] = c;
                    h_out[off] = h;
                }
            }
        }
    }
}

extern "C" void kernel_launch(void* const* d_in, const int* in_sizes, int n_in,
                              void* d_out, int out_size, void* d_ws, size_t ws_size,
                              hipStream_t stream) {
    const float* c_old = (const float*)d_in[0];
    const float* h_old = (const float*)d_in[1];
    const float* x     = (const float*)d_in[2];
    const float* Wf    = (const float*)d_in[3];
    const float* bf_   = (const float*)d_in[4];
    const float* Wi    = (const float*)d_in[5];
    const float* bi_   = (const float*)d_in[6];
    const float* Wo    = (const float*)d_in[7];
    const float* bo_   = (const float*)d_in[8];
    const float* Wg    = (const float*)d_in[9];
    const float* bg_   = (const float*)d_in[10];

    unsigned short* t  = (unsigned short*)d_ws;                           // 32 MB
    unsigned short* Wp = (unsigned short*)d_ws + (size_t)B_DIM * K_DIM;   // 64 MB

    float* c_out = (float*)d_out;
    float* h_out = (float*)d_out + (size_t)B_DIM * NOUT;

    pack_kernel<<<PACK_BLOCKS, 256, 0, stream>>>(x, h_old, Wf, Wi, Wo, Wg, t, Wp);

    lstm_gemm_kernel<<<dim3((B_DIM / BM) * (NG / BN)), dim3(512), 0, stream>>>(
        t, Wp, bf_, bi_, bo_, bg_, c_old, c_out, h_out);
}

// Round 8
// 553.899 us; speedup vs baseline: 1.1526x; 1.0171x over previous
//
#include <hip/hip_runtime.h>
#include <cstdint>

// LSTM cell: B=4096, N_IN=2048, N_OUT=2048.
// gates = [x|h_old](4096x4096) @ Wp^T + b ; Wp rows gate-interleaved: Wp[4j+q]=W_q[j].
// R11 = R10 resubmitted verbatim (infra failure, never measured):
//   pack: R8's flat 24576-block version (nt-loads + v_cvt_pk_bf16_f32, plain
//         stores). Measured gap (total - gemm): R4 209us / R8 165us / R9 187us
//         -> the flat nt+cvtpk pack is best; grid-stride lost 22us (TLP).
//   gemm: R9 loop byte-identical (376us, FETCH 214MB) MINUS s_setprio.
//         T5 is structure-conditional (m190: -14TF on non-functioning 8-phase;
//         ours measures 731 TF = 2-phase level), so setprio likely hurts here.
// ws layout: t bf16 (32MB) @0, Wp bf16 (64MB) @32MB. Requires ws_size >= 96MB.

#define B_DIM 4096
#define NIN   2048
#define NOUT  2048
#define K_DIM 4096   // NIN + NOUT
#define NG    8192   // 4 * NOUT

#define BM 256
#define BN 256
#define BK 64
#define NT      (K_DIM / BK)   // 64 K-tiles
#define NSTREAM (NT * 4)       // 256 half-tiles in the staging stream

typedef __attribute__((ext_vector_type(8))) short bf16x8;  // 8 bf16 = 4 VGPRs
typedef __attribute__((ext_vector_type(4))) float f32x4;
typedef __attribute__((ext_vector_type(4))) float fx4;

__device__ inline uint32_t cvtpk(float a, float b) {   // lo16=bf16(a), hi16=bf16(b), RNE
    uint32_t r;
    asm("v_cvt_pk_bf16_f32 %0, %1, %2" : "=v"(r) : "v"(a), "v"(b));
    return r;
}

__device__ inline float sel4(float a, float b, float c, float d, int s) {
    float x = (s & 1) ? b : a;
    float y = (s & 1) ? d : c;
    return (s & 2) ? y : x;
}

// ---- combined pack kernel (R8 version: flat grid, nt-loads, cvt_pk) ----
#define TBLK ((B_DIM * K_DIM / 8) / 256)   // 8192
#define WBLK ((NG * K_DIM / 8) / 256)      // 16384
__global__ void pack_kernel(const float* __restrict__ x,
                            const float* __restrict__ h_old,
                            const float* __restrict__ Wf, const float* __restrict__ Wi,
                            const float* __restrict__ Wo, const float* __restrict__ Wg,
                            unsigned short* __restrict__ t,
                            unsigned short* __restrict__ Wp) {
    const float* src;
    unsigned short* dst;
    int idx;
    if (blockIdx.x < TBLK) {
        idx = blockIdx.x * 256 + threadIdx.x;
        int b = idx >> 9;                                 // K/8 = 512 chunks/row
        int k = (idx & 511) << 3;
        src = (k < NIN) ? (x + (size_t)b * NIN + k)
                        : (h_old + (size_t)b * NOUT + (k - NIN));
        dst = t;
    } else {
        idx = (blockIdx.x - TBLK) * 256 + threadIdx.x;
        int row = idx >> 9;
        int k = (idx & 511) << 3;
        int jf = row >> 2, q = row & 3;
        src = ((q == 0) ? Wf : (q == 1) ? Wi : (q == 2) ? Wo : Wg)
              + (size_t)jf * K_DIM + k;
        dst = Wp;
    }
    // nt-loads: inputs read-once; keep them out of L2/L3 so t/Wp stay resident.
    fx4 lo = __builtin_nontemporal_load((const fx4*)src);
    fx4 hi = __builtin_nontemporal_load(((const fx4*)src) + 1);
    uint4 o;
    o.x = cvtpk(lo.x, lo.y);
    o.y = cvtpk(lo.z, lo.w);
    o.z = cvtpk(hi.x, hi.y);
    o.w = cvtpk(hi.z, hi.w);
    ((uint4*)dst)[idx] = o;   // plain store: t/Wp cached for the GEMM
}

#define GL2LDS(g, l) \
    __builtin_amdgcn_global_load_lds((const __attribute__((address_space(1))) void*)(g), \
                                     (__attribute__((address_space(3))) void*)(l), 16, 0, 0)

#define ASM_VMCNT4() asm volatile("s_waitcnt vmcnt(4)" ::: "memory")
#define ASM_VMCNT0() asm volatile("s_waitcnt vmcnt(0)" ::: "memory")
#define ASM_LGKM0()  asm volatile("s_waitcnt lgkmcnt(0)" ::: "memory")
#define BAR()        __builtin_amdgcn_s_barrier()

// Staging stream: half-tile idx -> tile=idx>>2, operand=idx&1 (0=A/T,1=B/Wp),
// half h=(idx>>1)&1 (rows h*128..h*128+127). Each thread: 2 x 16B loads.
// LDS dest linear (tid*16B); global source chunk pre-swizzled: c = (tid&7)^((tid>>3)&7).
#define STAGE(idx_) do {                                                          \
    const int _i = (idx_);                                                        \
    if (_i < NSTREAM) {                                                           \
        const int _tile = _i >> 2;                                                \
        const int _h    = (_i >> 1) & 1;                                          \
        const int _buf  = _tile & 1;                                              \
        const unsigned short* _g = ((_i & 1) ? Wg : Tg)                           \
                                   + (size_t)(_h * 128) * K_DIM + _tile * BK;     \
        unsigned short* _l = ((_i & 1) ? Bs : As)                                 \
                             + _buf * (BM * BK) + _h * 8192 + ldst;               \
        GL2LDS(_g, _l);                                                           \
        GL2LDS(_g + (size_t)64 * K_DIM, _l + 4096);                               \
    }                                                                             \
} while (0)

// ---- fused GEMM + LSTM epilogue: 256x256 tile, 8 waves, 8-phase schedule ----
__global__ __launch_bounds__(512, 1)
void lstm_gemm_kernel(const unsigned short* __restrict__ T,   // (B, K) bf16
                      const unsigned short* __restrict__ Wp,  // (NG, K) bf16
                      const float* __restrict__ bf_, const float* __restrict__ bi_,
                      const float* __restrict__ bo_, const float* __restrict__ bg_,
                      const float* __restrict__ c_old,
                      float* __restrict__ c_out, float* __restrict__ h_out) {
    __shared__ __align__(16) unsigned short As[2 * BM * BK];  // 64 KB
    __shared__ __align__(16) unsigned short Bs[2 * BN * BK];  // 64 KB

    const int tid  = threadIdx.x;
    const int lane = tid & 63;
    const int w    = tid >> 6;     // 0..7
    const int wr   = w >> 2;       // 0..1 (M)
    const int wc   = w & 3;        // 0..3 (N)

    // 8m x 8n region per XCD (bid&7 = XCD under round-robin dispatch).
    // Concurrent 32 blocks/XCD form an 8m x 4n rectangle: 8 same-L2 readers per
    // A-panel, 4 per B-panel; K-slice working set ~600KB fits the 4MB XCD L2.
    const int bid   = blockIdx.x;
    const int xcd   = bid & 7;
    const int intra = bid >> 3;                        // 0..63
    const int mi    = (xcd >> 2) * 8 + (intra & 7);    // 0..15
    const int ni    = (xcd & 3) * 8 + (intra >> 3);    // 0..31
    const int m0    = mi * BM;
    const int n0    = ni * BN;

    // staging per-thread constants
    const int rloc = tid >> 3;                                   // row 0..63
    const int coff = ((tid & 7) ^ ((tid >> 3) & 7)) << 3;        // swizzled src chunk
    const unsigned short* Tg = T  + (size_t)(m0 + rloc) * K_DIM + coff;
    const unsigned short* Wg = Wp + (size_t)(n0 + rloc) * K_DIM + coff;
    const int ldst = tid * 8;   // element offset within (buf, half) block

    // frag-read constants: chunk = (s*4 + ksel) ^ (row&7), row&7 == lane&7 here
    const int rsel = lane & 15, ksel = lane >> 4;
    const int cs0 = (ksel)     ^ (lane & 7);
    const int cs1 = (4 + ksel) ^ (lane & 7);
    const int aidx = (wr * 128 + rsel) * 8;   // + i*128 (+ 64*8 for half1) + cs
    const int bidx = (wc * 64  + rsel) * 8;   // + j*128 (+ 32*8 for half1) + cs

    const bf16x8* Av = (const bf16x8*)As;
    const bf16x8* Bv = (const bf16x8*)Bs;

    f32x4 acc[8][4];
#pragma unroll
    for (int i = 0; i < 8; ++i)
#pragma unroll
        for (int j = 0; j < 4; ++j)
            acc[i][j] = (f32x4){0.f, 0.f, 0.f, 0.f};

    // ---- prologue: stream 0..5 (tile0 complete + tile1 A0,B0), land tile0 ----
    STAGE(0); STAGE(1); STAGE(2); STAGE(3); STAGE(4); STAGE(5);
    ASM_VMCNT4();
    BAR();

    bf16x8 a0[4][2], a1[4][2], bfr[2][2];

#pragma unroll 2
    for (int t = 0; t < NT; ++t) {
        const int bo = (t & 1) * 2048;   // bf16x8 buffer offset

        // ---- P1: read A-half0 + B-half0, stage (t+1).A1 ----
#pragma unroll
        for (int i = 0; i < 4; ++i) {
            a0[i][0] = Av[bo + aidx + i * 128 + cs0];
            a0[i][1] = Av[bo + aidx + i * 128 + cs1];
        }
#pragma unroll
        for (int j = 0; j < 2; ++j) {
            bfr[j][0] = Bv[bo + bidx + j * 128 + cs0];
            bfr[j][1] = Bv[bo + bidx + j * 128 + cs1];
        }
        STAGE(4 * t + 6);
        BAR();
        ASM_LGKM0();
#pragma unroll
        for (int i = 0; i < 4; ++i)
#pragma unroll
            for (int j = 0; j < 2; ++j)
#pragma unroll
                for (int s = 0; s < 2; ++s)
                    acc[i][j] = __builtin_amdgcn_mfma_f32_16x16x32_bf16(
                        a0[i][s], bfr[j][s], acc[i][j], 0, 0, 0);
        BAR();

        // ---- P2: read A-half1, stage (t+1).B1 ----
#pragma unroll
        for (int i = 0; i < 4; ++i) {
            a1[i][0] = Av[bo + aidx + 512 + i * 128 + cs0];
            a1[i][1] = Av[bo + aidx + 512 + i * 128 + cs1];
        }
        STAGE(4 * t + 7);
        BAR();
        ASM_LGKM0();
#pragma unroll
        for (int i = 0; i < 4; ++i)
#pragma unroll
            for (int j = 0; j < 2; ++j)
#pragma unroll
                for (int s = 0; s < 2; ++s)
                    acc[4 + i][j] = __builtin_amdgcn_mfma_f32_16x16x32_bf16(
                        a1[i][s], bfr[j][s], acc[4 + i][j], 0, 0, 0);
        BAR();

        // ---- P3: read B-half1, stage (t+2).A0 ----
#pragma unroll
        for (int j = 0; j < 2; ++j) {
            bfr[j][0] = Bv[bo + bidx + 256 + j * 128 + cs0];
            bfr[j][1] = Bv[bo + bidx + 256 + j * 128 + cs1];
        }
        STAGE(4 * t + 8);
        BAR();
        ASM_LGKM0();
#pragma unroll
        for (int i = 0; i < 4; ++i)
#pragma unroll
            for (int j = 0; j < 2; ++j)
#pragma unroll
                for (int s = 0; s < 2; ++s)
                    acc[4 + i][2 + j] = __builtin_amdgcn_mfma_f32_16x16x32_bf16(
                        a1[i][s], bfr[j][s], acc[4 + i][2 + j], 0, 0, 0);
        BAR();

        // ---- P4: no reads (A-half0 kept in regs), stage (t+2).B0 ----
        STAGE(4 * t + 9);
        BAR();
#pragma unroll
        for (int s = 0; s < 2; ++s)
#pragma unroll
            for (int i = 0; i < 4; ++i)
#pragma unroll
                for (int j = 0; j < 2; ++j)
                    acc[i][2 + j] = __builtin_amdgcn_mfma_f32_16x16x32_bf16(
                        a0[i][s], bfr[j][s], acc[i][2 + j], 0, 0, 0);
        if (t < NT - 2) { ASM_VMCNT4(); } else { ASM_VMCNT0(); }
        BAR();
    }

    // ---- epilogue (plain loads/stores — R4 verbatim) ----
    // C/D map (16x16x32): col = lane&15, row = (lane>>4)*4 + r.
    // col n = n0+wc*64+16j+(lane&15): gate q = n&3 = lane&3, feature = n>>2.
    const int q = lane & 3;
    const float* bsrc = (q == 0) ? bf_ : (q == 1) ? bi_ : (q == 2) ? bo_ : bg_;
    const int colbase = n0 + wc * 64 + (lane & 15);
    float bias[4];
#pragma unroll
    for (int j = 0; j < 4; ++j)
        bias[j] = bsrc[(colbase + 16 * j) >> 2];

    const int rowbase = m0 + wr * 128 + 4 * (lane >> 4);
#pragma unroll
    for (int i = 0; i < 8; ++i) {
#pragma unroll
        for (int j = 0; j < 4; ++j) {
            const int featbase = (n0 + wc * 64 + 16 * j) >> 2;
#pragma unroll
            for (int r = 0; r < 4; ++r) {
                float z = acc[i][j][r] + bias[j];
                float v;
                if (q == 3) {                         // tanh for gate g
                    v = 1.f - 2.f / (__expf(2.f * z) + 1.f);
                } else {                              // sigmoid for f,i,o
                    v = 1.f / (1.f + __expf(-z));
                }
                float v1 = __shfl_xor(v, 1);
                float v2 = __shfl_xor(v, 2);
                float v3 = __shfl_xor(v, 3);
                float fg = sel4(v, v1, v2, v3, q);
                float ig = sel4(v, v1, v2, v3, q ^ 1);
                float og = sel4(v, v1, v2, v3, q ^ 2);
                float gg = sel4(v, v1, v2, v3, q ^ 3);
                if ((lane & 3) == r) {
                    const int row  = rowbase + 16 * i + r;
                    const int feat = featbase + ((lane & 15) >> 2);
                    const size_t off = (size_t)row * NOUT + feat;
                    float co = c_old[off];
                    float c  = fg * co + ig * gg;
                    float h  = og * (1.f - 2.f / (__expf(2.f * c) + 1.f));
                    c_out[off] = c;
                    h_out[off] = h;
                }
            }
        }
    }
}

extern "C" void kernel_launch(void* const* d_in, const int* in_sizes, int n_in,
                              void* d_out, int out_size, void* d_ws, size_t ws_size,
                              hipStream_t stream) {
    const float* c_old = (const float*)d_in[0];
    const float* h_old = (const float*)d_in[1];
    const float* x     = (const float*)d_in[2];
    const float* Wf    = (const float*)d_in[3];
    const float* bf_   = (const float*)d_in[4];
    const float* Wi    = (const float*)d_in[5];
    const float* bi_   = (const float*)d_in[6];
    const float* Wo    = (const float*)d_in[7];
    const float* bo_   = (const float*)d_in[8];
    const float* Wg    = (const float*)d_in[9];
    const float* bg_   = (const float*)d_in[10];

    unsigned short* t  = (unsigned short*)d_ws;                           // 32 MB
    unsigned short* Wp = (unsigned short*)d_ws + (size_t)B_DIM * K_DIM;   // 64 MB

    float* c_out = (float*)d_out;
    float* h_out = (float*)d_out + (size_t)B_DIM * NOUT;

    pack_kernel<<<TBLK + WBLK, 256, 0, stream>>>(x, h_old, Wf, Wi, Wo, Wg, t, Wp);

    lstm_gemm_kernel<<<dim3((B_DIM / BM) * (NG / BN)), dim3(512), 0, stream>>>(
        t, Wp, bf_, bi_, bo_, bg_, c_old, c_out, h_out);
}